// Round 6
// baseline (443.607 us; speedup 1.0000x reference)
//
#include <hip/hip_runtime.h>
#include <hip/hip_cooperative_groups.h>
#include <math.h>

namespace cg = cooperative_groups;

#define M_ 3
#define B_ 128
#define T_ 512
#define D_ 1024
#define P_ 256
#define TC 2

#define NPOOL   (M_ * B_ * TC)     // 768 pool blocks
#define NW1T    192                // W1-transpose rider blocks (4 tiles each)
#define NW2     64                 // W2 cast rider blocks
#define NBLK    (NPOOL + NW1T + NW2)   // 1024 = 4 blocks/CU co-resident

typedef __attribute__((ext_vector_type(8))) short short8v;   // 8 bf16 (4 VGPRs)
typedef __attribute__((ext_vector_type(4))) float f32x4;

// bf16 round-to-nearest-even from f32 bits
__device__ __forceinline__ unsigned int f2bf(float f) {
    unsigned int x = __float_as_uint(f);
    return (x + 0x7fffu + ((x >> 16) & 1u)) >> 16;
}

// ---------------- phase A: pool one (m,b,tc) stripe ----------------
__device__ __forceinline__ void pool_block(const float* __restrict__ feats,
                                           float* __restrict__ partial,
                                           int blk, int tid) {
    int tc = blk & (TC - 1);
    int mb = blk / TC;
    const int TSTEP = T_ / TC;                       // 256
    const int LDQ = D_ / 4;
    const float4* src = (const float4*)feats + ((size_t)mb * T_ + (size_t)tc * TSTEP) * LDQ + tid;
    float4 a0 = make_float4(0.f, 0.f, 0.f, 0.f);
    float4 a1 = a0, a2 = a0, a3 = a0, a4 = a0, a5 = a0, a6 = a0, a7 = a0;
    for (int t = 0; t < TSTEP; t += 8) {
        float4 v0 = src[0 * LDQ];
        float4 v1 = src[1 * LDQ];
        float4 v2 = src[2 * LDQ];
        float4 v3 = src[3 * LDQ];
        float4 v4 = src[4 * LDQ];
        float4 v5 = src[5 * LDQ];
        float4 v6 = src[6 * LDQ];
        float4 v7 = src[7 * LDQ];
        src += 8 * LDQ;
        a0.x += v0.x; a0.y += v0.y; a0.z += v0.z; a0.w += v0.w;
        a1.x += v1.x; a1.y += v1.y; a1.z += v1.z; a1.w += v1.w;
        a2.x += v2.x; a2.y += v2.y; a2.z += v2.z; a2.w += v2.w;
        a3.x += v3.x; a3.y += v3.y; a3.z += v3.z; a3.w += v3.w;
        a4.x += v4.x; a4.y += v4.y; a4.z += v4.z; a4.w += v4.w;
        a5.x += v5.x; a5.y += v5.y; a5.z += v5.z; a5.w += v5.w;
        a6.x += v6.x; a6.y += v6.y; a6.z += v6.z; a6.w += v6.w;
        a7.x += v7.x; a7.y += v7.y; a7.z += v7.z; a7.w += v7.w;
    }
    float4 s;
    s.x = ((a0.x + a1.x) + (a2.x + a3.x)) + ((a4.x + a5.x) + (a6.x + a7.x));
    s.y = ((a0.y + a1.y) + (a2.y + a3.y)) + ((a4.y + a5.y) + (a6.y + a7.y));
    s.z = ((a0.z + a1.z) + (a2.z + a3.z)) + ((a4.z + a5.z) + (a6.z + a7.z));
    s.w = ((a0.w + a1.w) + (a2.w + a3.w)) + ((a4.w + a5.w) + (a6.w + a7.w));
    ((float4*)partial)[((size_t)mb * TC + tc) * (D_ / 4) + tid] = s;
}

// ---------------- phase A rider: W1 [m][k][e] f32 -> w1t [m][e][k] bf16 ----------------
__device__ __forceinline__ void w1t_block(const float* __restrict__ W1,
                                          short* __restrict__ w1t,
                                          int bid, int tid, float (*ldsf)[68]) {
    for (int i = 0; i < 4; ++i) {
        int tile = bid * 4 + i;            // 0..767
        int et = tile & 15;
        int kt = (tile >> 4) & 15;
        int mm = tile >> 8;
        int k0 = kt * 64, ee0 = et * 64;
#pragma unroll
        for (int sv = 0; sv < 4; ++sv) {
            int idx = sv * 256 + tid;
            int row = idx >> 4;
            int c4  = idx & 15;
            float4 v = *(const float4*)(W1 + (size_t)mm * D_ * D_ + (size_t)(k0 + row) * D_ + ee0 + c4 * 4);
            *(float4*)&ldsf[row][c4 * 4] = v;
        }
        __syncthreads();
        int er = tid >> 2;
        int ks = (tid & 3) * 16;
        short8v v0, v1;
#pragma unroll
        for (int j = 0; j < 8; ++j) v0[j] = (short)f2bf(ldsf[ks + j][er]);
#pragma unroll
        for (int j = 0; j < 8; ++j) v1[j] = (short)f2bf(ldsf[ks + 8 + j][er]);
        size_t ob = ((size_t)mm * D_ + ee0 + er) * D_ + k0 + ks;
        *(short8v*)(w1t + ob)     = v0;
        *(short8v*)(w1t + ob + 8) = v1;
        __syncthreads();
    }
}

// ---------------- phase A rider: W2 -> packed bf16 pairs ----------------
__device__ __forceinline__ void w2c_block(const float* __restrict__ W2,
                                          unsigned int* __restrict__ w2p,
                                          int bid, int tid) {
    const int TOT = M_ * (D_ / 2) * P_;    // 393216
    for (int i = bid * 256 + tid; i < TOT; i += NW2 * 256) {
        int p  = i & (P_ - 1);
        int k2 = (i >> 8) & (D_ / 2 - 1);
        int m  = i >> 17;
        size_t base = (size_t)m * D_ * P_ + (size_t)(2 * k2) * P_ + p;
        float f0 = W2[base];
        float f1 = W2[base + P_];
        w2p[i] = f2bf(f0) | (f2bf(f1) << 16);
    }
}

// ---------------- phase B: h = gelu(mean(partial) @ W1 + b1), bf16 MFMA ----------------
// tile 32x64, BK=64, 4 waves; LDS XOR-swizzled (16B chunk ^= row&7).
__device__ __forceinline__ void gemm1_block(const float* __restrict__ partial,
                                            const short* __restrict__ w1t,
                                            const float* __restrict__ b1,
                                            float* __restrict__ h,
                                            int m, int by, int bx, int tid,
                                            char* AsB, char* BsB) {
    int b0 = by * 32;
    int e0 = bx * 64;
    int l   = tid & 63;
    int w   = tid >> 6;
    int wr  = w & 1, wc = w >> 1;

    int arow = tid >> 3;          // 0..31 A row
    int k8   = tid & 7;           // 16B chunk
    int bcol = tid >> 2;          // 0..63 B row (= W1 col)
    int bj   = tid & 3;           // 32B segment

    const float* Abase = partial + ((size_t)(m * B_ + b0 + arow) * TC) * D_ + k8 * 8;
    const short* Bbase = w1t + ((size_t)m * D_ + e0 + bcol) * D_ + bj * 16;

    short8v* AsW  = (short8v*)(AsB + arow * 128 + ((k8 ^ (arow & 7)) << 4));
    short8v* BsW0 = (short8v*)(BsB + bcol * 128 + (((2 * bj)     ^ (bcol & 7)) << 4));
    short8v* BsW1 = (short8v*)(BsB + bcol * 128 + (((2 * bj + 1) ^ (bcol & 7)) << 4));

    f32x4 acc0 = {0.f, 0.f, 0.f, 0.f};
    f32x4 acc1 = {0.f, 0.f, 0.f, 0.f};
    const float inv = 1.0f / (float)T_;

    int ar  = wr * 16 + (l & 15);
    int bc0 = wc * 32 + (l & 15);
    int bc1 = bc0 + 16;
    int lh  = l >> 4;

    for (int it = 0; it < 16; ++it) {
        int k0 = it * 64;
        float4 p00 = *(const float4*)(Abase + k0);
        float4 p01 = *(const float4*)(Abase + k0 + 4);
        float4 p10 = *(const float4*)(Abase + D_ + k0);
        float4 p11 = *(const float4*)(Abase + D_ + k0 + 4);
        short8v bv0 = *(const short8v*)(Bbase + k0);
        short8v bv1 = *(const short8v*)(Bbase + k0 + 8);
        __syncthreads();
        short8v av;
        av[0] = (short)f2bf((p00.x + p10.x) * inv);
        av[1] = (short)f2bf((p00.y + p10.y) * inv);
        av[2] = (short)f2bf((p00.z + p10.z) * inv);
        av[3] = (short)f2bf((p00.w + p10.w) * inv);
        av[4] = (short)f2bf((p01.x + p11.x) * inv);
        av[5] = (short)f2bf((p01.y + p11.y) * inv);
        av[6] = (short)f2bf((p01.z + p11.z) * inv);
        av[7] = (short)f2bf((p01.w + p11.w) * inv);
        *AsW  = av;
        *BsW0 = bv0;
        *BsW1 = bv1;
        __syncthreads();
#pragma unroll
        for (int kk = 0; kk < 2; ++kk) {
            int ch = kk * 4 + lh;
            short8v af  = *(const short8v*)(AsB + ar  * 128 + ((ch ^ (ar  & 7)) << 4));
            short8v bf0 = *(const short8v*)(BsB + bc0 * 128 + ((ch ^ (bc0 & 7)) << 4));
            short8v bf1 = *(const short8v*)(BsB + bc1 * 128 + ((ch ^ (bc1 & 7)) << 4));
            acc0 = __builtin_amdgcn_mfma_f32_16x16x32_bf16(af, bf0, acc0, 0, 0, 0);
            acc1 = __builtin_amdgcn_mfma_f32_16x16x32_bf16(af, bf1, acc1, 0, 0, 0);
        }
    }

    int colBase = e0 + wc * 32 + (l & 15);
    int rowBase = b0 + wr * 16 + lh * 4;
    const float is2 = 0.70710678118654752f;
#pragma unroll
    for (int n = 0; n < 2; ++n) {
        f32x4 acc = n ? acc1 : acc0;
        int col = colBase + n * 16;
        float bb = b1[m * D_ + col];
#pragma unroll
        for (int r = 0; r < 4; ++r) {
            float x = acc[r] + bb;
            float gx = 0.5f * x * (1.0f + erff(x * is2));
            h[(size_t)(m * B_ + rowBase + r) * D_ + col] = gx;
        }
    }
}

// ---------------- phase C: z = h @ W2 + b2, LN, L2-normalize (2 rows, 256 thr) ----------------
__device__ __forceinline__ void gemm2_block(const float* __restrict__ h,
                                            const unsigned int* __restrict__ w2p,
                                            const float* __restrict__ b2,
                                            const float* __restrict__ gamma,
                                            const float* __restrict__ beta,
                                            float* __restrict__ out,
                                            int m, int b0, int tid,
                                            float* hs0, float* hs1, float* red) {
    const float* hrow = h + (size_t)(m * B_ + b0) * D_;
    ((float4*)hs0)[tid] = ((const float4*)hrow)[tid];
    ((float4*)hs1)[tid] = ((const float4*)(hrow + D_))[tid];
    __syncthreads();
    const unsigned int* Wp = w2p + (size_t)m * (D_ / 2) * P_ + tid;   // p = tid
    float acc0 = 0.f, acc1 = 0.f;
#pragma unroll 8
    for (int k2 = 0; k2 < D_ / 2; ++k2) {
        unsigned int u = Wp[(size_t)k2 * P_];
        float w0 = __uint_as_float(u << 16);
        float w1 = __uint_as_float(u & 0xffff0000u);
        float h00 = hs0[2 * k2], h01 = hs0[2 * k2 + 1];
        float h10 = hs1[2 * k2], h11 = hs1[2 * k2 + 1];
        acc0 += h00 * w0 + h01 * w1;
        acc1 += h10 * w0 + h11 * w1;
    }
    int lane = tid & 63, w = tid >> 6;
    float bias = b2[m * P_ + tid], gm = gamma[m * P_ + tid], bt = beta[m * P_ + tid];
    float z0 = acc0 + bias, z1 = acc1 + bias;

    float s10 = z0, s20 = z0 * z0, s11 = z1, s21 = z1 * z1;
    for (int off = 32; off; off >>= 1) {
        s10 += __shfl_xor(s10, off); s20 += __shfl_xor(s20, off);
        s11 += __shfl_xor(s11, off); s21 += __shfl_xor(s21, off);
    }
    if (lane == 0) { red[w] = s10; red[4 + w] = s20; red[8 + w] = s11; red[12 + w] = s21; }
    __syncthreads();
    {
        float s1 = (red[0] + red[1]) + (red[2] + red[3]);
        float s2 = (red[4] + red[5]) + (red[6] + red[7]);
        float mu = s1 * (1.0f / P_), var = s2 * (1.0f / P_) - mu * mu;
        float iv = 1.0f / sqrtf(var + 1e-5f);
        z0 = (z0 - mu) * iv * gm + bt;
        float s1b = (red[8] + red[9]) + (red[10] + red[11]);
        float s2b = (red[12] + red[13]) + (red[14] + red[15]);
        float mub = s1b * (1.0f / P_), varb = s2b * (1.0f / P_) - mub * mub;
        float ivb = 1.0f / sqrtf(varb + 1e-5f);
        z1 = (z1 - mub) * ivb * gm + bt;
    }
    __syncthreads();   // before reusing red
    float t0 = z0 * z0, t1 = z1 * z1;
    for (int off = 32; off; off >>= 1) { t0 += __shfl_xor(t0, off); t1 += __shfl_xor(t1, off); }
    if (lane == 0) { red[w] = t0; red[4 + w] = t1; }
    __syncthreads();
    float n0 = sqrtf((red[0] + red[1]) + (red[2] + red[3]));
    float n1 = sqrtf((red[4] + red[5]) + (red[6] + red[7]));
    out[(size_t)(m * B_ + b0) * P_ + tid]     = z0 / fmaxf(n0, 1e-12f);
    out[(size_t)(m * B_ + b0 + 1) * P_ + tid] = z1 / fmaxf(n1, 1e-12f);
}

// ================= fused cooperative kernel =================
__global__ __launch_bounds__(256, 4) void fused_all(const float* feats, const float* W1,
                                                    const float* W2, const float* b1,
                                                    const float* b2, const float* gamma,
                                                    const float* beta, float* partial,
                                                    short* w1t, unsigned int* w2p,
                                                    float* hbuf, float* out) {
    __shared__ __align__(16) char smem[17408];
    int blk = blockIdx.x;
    int tid = threadIdx.x;

    // Phase A
    if (blk < NPOOL) {
        pool_block(feats, partial, blk, tid);
    } else if (blk < NPOOL + NW1T) {
        w1t_block(W1, w1t, blk - NPOOL, tid, (float(*)[68])smem);
    } else {
        w2c_block(W2, w2p, blk - NPOOL - NW1T, tid);
    }
    cg::this_grid().sync();

    // Phase B: 192 blocks
    if (blk < 192) {
        int m = blk >> 6, rem = blk & 63;
        gemm1_block(partial, w1t, b1, hbuf, m, rem >> 4, rem & 15, tid,
                    smem, smem + 4096);
    }
    cg::this_grid().sync();

    // Phase C: 192 blocks
    if (blk < 192) {
        int m = blk >> 6, b0 = (blk & 63) * 2;
        gemm2_block(hbuf, w2p, b2, gamma, beta, out, m, b0, tid,
                    (float*)smem, (float*)(smem + 4096), (float*)(smem + 8192));
    }
}

// ================= fallback standalone kernels =================
__global__ __launch_bounds__(256) void pool_cast_k(const float* feats, const float* W1,
                                                   const float* W2, float* partial,
                                                   short* w1t, unsigned int* w2p) {
    __shared__ __align__(16) char smem[17408];
    int blk = blockIdx.x, tid = threadIdx.x;
    if (blk < NPOOL) pool_block(feats, partial, blk, tid);
    else if (blk < NPOOL + NW1T) w1t_block(W1, w1t, blk - NPOOL, tid, (float(*)[68])smem);
    else w2c_block(W2, w2p, blk - NPOOL - NW1T, tid);
}

__global__ __launch_bounds__(256) void gemm1_k(const float* partial, const short* w1t,
                                               const float* b1, float* hbuf) {
    __shared__ __align__(16) char smem[12288];
    int blk = blockIdx.x;
    int m = blk >> 6, rem = blk & 63;
    gemm1_block(partial, w1t, b1, hbuf, m, rem >> 4, rem & 15, threadIdx.x,
                smem, smem + 4096);
}

__global__ __launch_bounds__(256) void gemm2_k(const float* hbuf, const unsigned int* w2p,
                                               const float* b2, const float* gamma,
                                               const float* beta, float* out) {
    __shared__ __align__(16) char smem[8320];
    int blk = blockIdx.x;
    int m = blk >> 6, b0 = (blk & 63) * 2;
    gemm2_block(hbuf, w2p, b2, gamma, beta, out, m, b0, threadIdx.x,
                (float*)smem, (float*)(smem + 4096), (float*)(smem + 8192));
}

extern "C" void kernel_launch(void* const* d_in, const int* in_sizes, int n_in,
                              void* d_out, int out_size, void* d_ws, size_t ws_size,
                              hipStream_t stream) {
    const float* feats = (const float*)d_in[0];
    const float* W1    = (const float*)d_in[1];
    const float* b1    = (const float*)d_in[2];
    const float* W2    = (const float*)d_in[3];
    const float* b2    = (const float*)d_in[4];
    const float* gamma = (const float*)d_in[5];
    const float* beta  = (const float*)d_in[6];
    float* out = (float*)d_out;

    float* wsf = (float*)d_ws;
    float*        partial = wsf;                                 // M*B*TC*D f32 (3 MB)
    unsigned int* w2p     = (unsigned int*)(wsf + 786432);       // M*(D/2)*P u32 (1.5 MB)
    float*        hbuf    = wsf + 786432 + 393216;               // M*B*D f32 (1.5 MB)
    short*        w1t     = (short*)(wsf + 786432 + 2 * 393216); // M*D*D bf16 (6 MB)

    void* kargs[] = {(void*)&feats, (void*)&W1, (void*)&W2, (void*)&b1, (void*)&b2,
                     (void*)&gamma, (void*)&beta, (void*)&partial, (void*)&w1t,
                     (void*)&w2p, (void*)&hbuf, (void*)&out};
    hipError_t e = hipLaunchCooperativeKernel((void*)fused_all, dim3(NBLK), dim3(256),
                                              kargs, 0, stream);
    if (e != hipSuccess) {
        // fallback: identical math, 3 serial launches
        pool_cast_k<<<NBLK, 256, 0, stream>>>(feats, W1, W2, partial, w1t, w2p);
        gemm1_k<<<192, 256, 0, stream>>>(partial, w1t, b1, hbuf);
        gemm2_k<<<192, 256, 0, stream>>>(hbuf, w2p, b2, gamma, beta, out);
    }
}

// Round 8
// 188.784 us; speedup vs baseline: 2.3498x; 2.3498x over previous
//
#include <hip/hip_runtime.h>
#include <math.h>

#define M_ 3
#define B_ 128
#define T_ 512
#define D_ 1024
#define P_ 256
#define TC 2            // t-chunks for the pooling kernel

#define NPOOL   (M_ * B_ * TC)     // 768 pool blocks
#define NW1T    192                // W1-transpose rider blocks (4 tiles each)
#define NW2     64                 // W2 cast rider blocks

typedef __attribute__((ext_vector_type(8))) short short8v;   // 8 bf16 (4 VGPRs)
typedef __attribute__((ext_vector_type(4))) float f32x4;

// bf16 round-to-nearest-even from f32 bits
__device__ __forceinline__ unsigned int f2bf(float f) {
    unsigned int x = __float_as_uint(f);
    return (x + 0x7fffu + ((x >> 16) & 1u)) >> 16;
}

// nontemporal float4 load via native ext-vector type (builtin rejects HIP_vector_type)
__device__ __forceinline__ float4 ntload4(const float4* p) {
    f32x4 v = __builtin_nontemporal_load((const f32x4*)p);
    return make_float4(v.x, v.y, v.z, v.w);
}

// ---------------- Kernel 1: pool partials + W1^T-bf16 + W2-bf16 riders ----------------
// blocks [0, NPOOL): sum 256 timesteps of one (m,b) row into partial.
//   feats is read-exactly-once -> nontemporal loads (no L2/L3 allocation).
// blocks [NPOOL, NPOOL+NW1T): transpose-cast W1 -> w1t[m][e][k] bf16 (4 64x64 tiles each).
// blocks [NPOOL+NW1T, +NW2): cast W2 -> packed bf16 pairs w2p (u32 [M][D/2][P]).
__global__ __launch_bounds__(256) void pool_and_cast(const float* __restrict__ feats,
                                                     const float* __restrict__ W1,
                                                     const float* __restrict__ W2,
                                                     float* __restrict__ partial,
                                                     short* __restrict__ w1t,
                                                     unsigned int* __restrict__ w2p) {
    __shared__ float ldsf[64][68];     // rider transpose buffer
    int blk = blockIdx.x;
    int tid = threadIdx.x;

    if (blk < NPOOL) {
        int tc = blk & (TC - 1);
        int mb = blk / TC;
        const int TSTEP = T_ / TC;                       // 256
        const int LDQ = D_ / 4;
        const float4* src = (const float4*)feats + ((size_t)mb * T_ + (size_t)tc * TSTEP) * LDQ + tid;
        float4 a0 = make_float4(0.f, 0.f, 0.f, 0.f);
        float4 a1 = a0, a2 = a0, a3 = a0, a4 = a0, a5 = a0, a6 = a0, a7 = a0;
        for (int t = 0; t < TSTEP; t += 8) {
            float4 v0 = ntload4(src + 0 * LDQ);
            float4 v1 = ntload4(src + 1 * LDQ);
            float4 v2 = ntload4(src + 2 * LDQ);
            float4 v3 = ntload4(src + 3 * LDQ);
            float4 v4 = ntload4(src + 4 * LDQ);
            float4 v5 = ntload4(src + 5 * LDQ);
            float4 v6 = ntload4(src + 6 * LDQ);
            float4 v7 = ntload4(src + 7 * LDQ);
            src += 8 * LDQ;
            a0.x += v0.x; a0.y += v0.y; a0.z += v0.z; a0.w += v0.w;
            a1.x += v1.x; a1.y += v1.y; a1.z += v1.z; a1.w += v1.w;
            a2.x += v2.x; a2.y += v2.y; a2.z += v2.z; a2.w += v2.w;
            a3.x += v3.x; a3.y += v3.y; a3.z += v3.z; a3.w += v3.w;
            a4.x += v4.x; a4.y += v4.y; a4.z += v4.z; a4.w += v4.w;
            a5.x += v5.x; a5.y += v5.y; a5.z += v5.z; a5.w += v5.w;
            a6.x += v6.x; a6.y += v6.y; a6.z += v6.z; a6.w += v6.w;
            a7.x += v7.x; a7.y += v7.y; a7.z += v7.z; a7.w += v7.w;
        }
        float4 s;
        s.x = ((a0.x + a1.x) + (a2.x + a3.x)) + ((a4.x + a5.x) + (a6.x + a7.x));
        s.y = ((a0.y + a1.y) + (a2.y + a3.y)) + ((a4.y + a5.y) + (a6.y + a7.y));
        s.z = ((a0.z + a1.z) + (a2.z + a3.z)) + ((a4.z + a5.z) + (a6.z + a7.z));
        s.w = ((a0.w + a1.w) + (a2.w + a3.w)) + ((a4.w + a5.w) + (a6.w + a7.w));
        ((float4*)partial)[((size_t)mb * TC + tc) * (D_ / 4) + tid] = s;
        return;
    }

    if (blk < NPOOL + NW1T) {
        // W1 [m][k][e] f32  ->  w1t [m][e][k] bf16 ; 64x64 tiles via LDS transpose
        int bid = blk - NPOOL;                 // 0..191
        for (int i = 0; i < 4; ++i) {
            int tile = bid * 4 + i;            // 0..767
            int et = tile & 15;
            int kt = (tile >> 4) & 15;
            int mm = tile >> 8;
            int k0 = kt * 64, ee0 = et * 64;
#pragma unroll
            for (int sv = 0; sv < 4; ++sv) {
                int idx = sv * 256 + tid;
                int row = idx >> 4;
                int c4  = idx & 15;
                float4 v = ntload4((const float4*)(W1 + (size_t)mm * D_ * D_ + (size_t)(k0 + row) * D_ + ee0 + c4 * 4));
                *(float4*)&ldsf[row][c4 * 4] = v;
            }
            __syncthreads();
            int er = tid >> 2;
            int ks = (tid & 3) * 16;
            short8v v0, v1;
#pragma unroll
            for (int j = 0; j < 8; ++j) v0[j] = (short)f2bf(ldsf[ks + j][er]);
#pragma unroll
            for (int j = 0; j < 8; ++j) v1[j] = (short)f2bf(ldsf[ks + 8 + j][er]);
            size_t ob = ((size_t)mm * D_ + ee0 + er) * D_ + k0 + ks;
            *(short8v*)(w1t + ob)     = v0;
            *(short8v*)(w1t + ob + 8) = v1;
            __syncthreads();
        }
        return;
    }

    // W2 cast: w2p[m][k2][p] = bf16(W2[m][2k2][p]) | bf16(W2[m][2k2+1][p])<<16
    {
        int bid = blk - NPOOL - NW1T;          // 0..63
        const int TOT = M_ * (D_ / 2) * P_;    // 393216
        for (int i = bid * 256 + tid; i < TOT; i += NW2 * 256) {
            int p  = i & (P_ - 1);
            int k2 = (i >> 8) & (D_ / 2 - 1);
            int m  = i >> 17;
            size_t base = (size_t)m * D_ * P_ + (size_t)(2 * k2) * P_ + p;
            float f0 = __builtin_nontemporal_load(W2 + base);
            float f1 = __builtin_nontemporal_load(W2 + base + P_);
            w2p[i] = f2bf(f0) | (f2bf(f1) << 16);
        }
    }
}

// ---------------- Kernel 2: h = gelu(mean(partial) @ W1 + b1), bf16 MFMA ----------------
// grid (D/64=16, B/32=4, M) = 192 blocks, 256 threads = 4 waves.
// Tile 32(rows) x 64(cols), BK=64. LDS XOR-swizzled (16B chunk ^= row&7).
__global__ __launch_bounds__(256) void gemm1_mfma(const float* __restrict__ partial,
                                                  const short* __restrict__ w1t,
                                                  const float* __restrict__ b1,
                                                  float* __restrict__ h) {
    __shared__ __align__(16) short As[32 * 64];   // [row][k] bf16, 128B rows
    __shared__ __align__(16) short Bs[64 * 64];   // [col][k] bf16, 128B rows
    int m  = blockIdx.z;
    int b0 = blockIdx.y * 32;
    int e0 = blockIdx.x * 64;
    int tid = threadIdx.x;
    int l   = tid & 63;
    int w   = tid >> 6;
    int wr  = w & 1, wc = w >> 1;

    int arow = tid >> 3;          // 0..31 A row
    int k8   = tid & 7;           // 16B chunk (8 bf16)
    int bcol = tid >> 2;          // 0..63 B "row" (= W1 col)
    int bj   = tid & 3;           // 32B segment (2 chunks)

    const float* Abase = partial + ((size_t)(m * B_ + b0 + arow) * TC) * D_ + k8 * 8;
    const short* Bbase = w1t + ((size_t)m * D_ + e0 + bcol) * D_ + bj * 16;

    char* AsB = (char*)As;
    char* BsB = (char*)Bs;
    short8v* AsW  = (short8v*)(AsB + arow * 128 + ((k8 ^ (arow & 7)) << 4));
    short8v* BsW0 = (short8v*)(BsB + bcol * 128 + (((2 * bj)     ^ (bcol & 7)) << 4));
    short8v* BsW1 = (short8v*)(BsB + bcol * 128 + (((2 * bj + 1) ^ (bcol & 7)) << 4));

    f32x4 acc0 = {0.f, 0.f, 0.f, 0.f};
    f32x4 acc1 = {0.f, 0.f, 0.f, 0.f};
    const float inv = 1.0f / (float)T_;

    int ar  = wr * 16 + (l & 15);
    int bc0 = wc * 32 + (l & 15);
    int bc1 = bc0 + 16;
    int lh  = l >> 4;             // 0..3

    for (int it = 0; it < 16; ++it) {
        int k0 = it * 64;
        float4 p00 = *(const float4*)(Abase + k0);
        float4 p01 = *(const float4*)(Abase + k0 + 4);
        float4 p10 = *(const float4*)(Abase + D_ + k0);
        float4 p11 = *(const float4*)(Abase + D_ + k0 + 4);
        short8v bv0 = *(const short8v*)(Bbase + k0);
        short8v bv1 = *(const short8v*)(Bbase + k0 + 8);
        __syncthreads();   // previous iteration's frag reads done
        short8v av;
        av[0] = (short)f2bf((p00.x + p10.x) * inv);
        av[1] = (short)f2bf((p00.y + p10.y) * inv);
        av[2] = (short)f2bf((p00.z + p10.z) * inv);
        av[3] = (short)f2bf((p00.w + p10.w) * inv);
        av[4] = (short)f2bf((p01.x + p11.x) * inv);
        av[5] = (short)f2bf((p01.y + p11.y) * inv);
        av[6] = (short)f2bf((p01.z + p11.z) * inv);
        av[7] = (short)f2bf((p01.w + p11.w) * inv);
        *AsW  = av;
        *BsW0 = bv0;
        *BsW1 = bv1;
        __syncthreads();
#pragma unroll
        for (int kk = 0; kk < 2; ++kk) {
            int ch = kk * 4 + lh;
            short8v af  = *(const short8v*)(AsB + ar  * 128 + ((ch ^ (ar  & 7)) << 4));
            short8v bf0 = *(const short8v*)(BsB + bc0 * 128 + ((ch ^ (bc0 & 7)) << 4));
            short8v bf1 = *(const short8v*)(BsB + bc1 * 128 + ((ch ^ (bc1 & 7)) << 4));
            acc0 = __builtin_amdgcn_mfma_f32_16x16x32_bf16(af, bf0, acc0, 0, 0, 0);
            acc1 = __builtin_amdgcn_mfma_f32_16x16x32_bf16(af, bf1, acc1, 0, 0, 0);
        }
    }

    // epilogue: C/D layout col=lane&15, row=(lane>>4)*4+reg  [m89-verified]
    int colBase = e0 + wc * 32 + (l & 15);
    int rowBase = b0 + wr * 16 + lh * 4;
    const float is2 = 0.70710678118654752f;
#pragma unroll
    for (int n = 0; n < 2; ++n) {
        f32x4 acc = n ? acc1 : acc0;
        int col = colBase + n * 16;
        float bb = b1[m * D_ + col];
#pragma unroll
        for (int r = 0; r < 4; ++r) {
            float x = acc[r] + bb;
            float gx = 0.5f * x * (1.0f + erff(x * is2));
            h[(size_t)(m * B_ + rowBase + r) * D_ + col] = gx;
        }
    }
}

// ---------------- Kernel 3: z = h @ W2 + b2, LN, L2-normalize; split-K x2, 512 thr ----------------
__global__ __launch_bounds__(512) void gemm2_ln(const float* __restrict__ h,
                                                const unsigned int* __restrict__ w2p,
                                                const float* __restrict__ b2,
                                                const float* __restrict__ gamma,
                                                const float* __restrict__ beta,
                                                float* __restrict__ out) {
    int m  = blockIdx.y;
    int b0 = blockIdx.x * 2;
    int tid  = threadIdx.x;
    int p    = tid & 255;
    int half = tid >> 8;
    int lane = tid & 63;
    int w    = (tid >> 6) & 3;

    __shared__ float accs[2][2][256];   // [half][row][p]
    __shared__ float redA[2][4];
    __shared__ float redB[2][4];
    __shared__ float redC[2][4];

    const unsigned int* Wp = w2p + (size_t)m * (D_ / 2) * P_ + (size_t)half * 256 * P_ + p;
    const float* hb = h + ((size_t)m * B_ + b0) * D_ + half * 512;

    float acc0 = 0.f, acc1 = 0.f;
#pragma unroll 8
    for (int q = 0; q < 128; ++q) {
        unsigned int u0 = Wp[(size_t)(2 * q) * P_];
        unsigned int u1 = Wp[(size_t)(2 * q + 1) * P_];
        float w0 = __uint_as_float(u0 << 16);
        float w1 = __uint_as_float(u0 & 0xffff0000u);
        float w2 = __uint_as_float(u1 << 16);
        float w3 = __uint_as_float(u1 & 0xffff0000u);
        float4 h0 = *(const float4*)(hb + 4 * q);          // uniform
        float4 h1 = *(const float4*)(hb + D_ + 4 * q);     // uniform
        acc0 += h0.x * w0 + h0.y * w1 + h0.z * w2 + h0.w * w3;
        acc1 += h1.x * w0 + h1.y * w1 + h1.z * w2 + h1.w * w3;
    }
    accs[half][0][p] = acc0;
    accs[half][1][p] = acc1;
    __syncthreads();

    int g = half;
    float z = accs[0][g][p] + accs[1][g][p] + b2[m * P_ + p];

    float s1 = z, s2 = z * z;
    for (int off = 32; off > 0; off >>= 1) {
        s1 += __shfl_xor(s1, off);
        s2 += __shfl_xor(s2, off);
    }
    if (lane == 0) { redA[g][w] = s1; redB[g][w] = s2; }
    __syncthreads();
    s1 = (redA[g][0] + redA[g][1]) + (redA[g][2] + redA[g][3]);
    s2 = (redB[g][0] + redB[g][1]) + (redB[g][2] + redB[g][3]);
    float mu  = s1 * (1.0f / P_);
    float var = s2 * (1.0f / P_) - mu * mu;
    float inv = 1.0f / sqrtf(var + 1e-5f);
    z = (z - mu) * inv * gamma[m * P_ + p] + beta[m * P_ + p];

    float s = z * z;
    for (int off = 32; off > 0; off >>= 1) s += __shfl_xor(s, off);
    if (lane == 0) redC[g][w] = s;
    __syncthreads();
    s = (redC[g][0] + redC[g][1]) + (redC[g][2] + redC[g][3]);
    float n = sqrtf(s);
    out[((size_t)m * B_ + b0 + g) * P_ + p] = z / fmaxf(n, 1e-12f);
}

extern "C" void kernel_launch(void* const* d_in, const int* in_sizes, int n_in,
                              void* d_out, int out_size, void* d_ws, size_t ws_size,
                              hipStream_t stream) {
    const float* feats = (const float*)d_in[0];
    const float* W1    = (const float*)d_in[1];
    const float* b1    = (const float*)d_in[2];
    const float* W2    = (const float*)d_in[3];
    const float* b2    = (const float*)d_in[4];
    const float* gamma = (const float*)d_in[5];
    const float* beta  = (const float*)d_in[6];
    float* out = (float*)d_out;

    float* wsf = (float*)d_ws;
    float*        partial = wsf;                                 // M*B*TC*D f32 (3 MB)
    unsigned int* w2p     = (unsigned int*)(wsf + 786432);       // M*(D/2)*P u32 (1.5 MB)
    float*        hbuf    = wsf + 786432 + 393216;               // M*B*D f32 (1.5 MB)
    short*        w1t     = (short*)(wsf + 786432 + 2 * 393216); // M*D*D bf16 (6 MB)
    // total ws: 12 MB

    pool_and_cast<<<NPOOL + NW1T + NW2, 256, 0, stream>>>(feats, W1, W2, partial, w1t, w2p);
    dim3 g2(D_ / 64, B_ / 32, M_);
    gemm1_mfma<<<g2, 256, 0, stream>>>(partial, w1t, b1, hbuf);
    dim3 g3(B_ / 2, M_);
    gemm2_ln<<<g3, 512, 0, stream>>>(hbuf, w2p, b2, gamma, beta, out);
}

// Round 9
// 186.778 us; speedup vs baseline: 2.3750x; 1.0107x over previous
//
#include <hip/hip_runtime.h>
#include <math.h>

#define M_ 3
#define B_ 128
#define T_ 512
#define D_ 1024
#define P_ 256
#define TC 4            // t-chunks for the pooling kernel (1536 pool blocks)

#define NPOOL   (M_ * B_ * TC)     // 1536 pool blocks
#define NW1T    192                // W1-transpose rider blocks (4 tiles each)
#define NW2     64                 // W2 cast rider blocks

typedef __attribute__((ext_vector_type(8))) short short8v;   // 8 bf16 (4 VGPRs)
typedef __attribute__((ext_vector_type(4))) float f32x4;

// bf16 round-to-nearest-even from f32 bits
__device__ __forceinline__ unsigned int f2bf(float f) {
    unsigned int x = __float_as_uint(f);
    return (x + 0x7fffu + ((x >> 16) & 1u)) >> 16;
}

// nontemporal float4 load via native ext-vector type (builtin rejects HIP_vector_type)
__device__ __forceinline__ float4 ntload4(const float4* p) {
    f32x4 v = __builtin_nontemporal_load((const f32x4*)p);
    return make_float4(v.x, v.y, v.z, v.w);
}

// ---------------- Kernel 1: pool partials + W1^T-bf16 + W2-bf16 riders ----------------
// blocks [0, NPOOL): sum 128 timesteps of one (m,b) row into partial (nt loads).
// blocks [NPOOL, NPOOL+NW1T): transpose-cast W1 -> w1t[m][e][k] bf16 (4 64x64 tiles each).
// blocks [NPOOL+NW1T, +NW2): cast W2 -> packed bf16 pairs w2p (u32 [M][D/2][P]).
__global__ __launch_bounds__(256) void pool_and_cast(const float* __restrict__ feats,
                                                     const float* __restrict__ W1,
                                                     const float* __restrict__ W2,
                                                     float* __restrict__ partial,
                                                     short* __restrict__ w1t,
                                                     unsigned int* __restrict__ w2p) {
    __shared__ float ldsf[64][68];     // rider transpose buffer
    int blk = blockIdx.x;
    int tid = threadIdx.x;

    if (blk < NPOOL) {
        int tc = blk & (TC - 1);
        int mb = blk / TC;
        const int TSTEP = T_ / TC;                       // 128
        const int LDQ = D_ / 4;
        const float4* src = (const float4*)feats + ((size_t)mb * T_ + (size_t)tc * TSTEP) * LDQ + tid;
        float4 a0 = make_float4(0.f, 0.f, 0.f, 0.f);
        float4 a1 = a0, a2 = a0, a3 = a0, a4 = a0, a5 = a0, a6 = a0, a7 = a0;
        for (int t = 0; t < TSTEP; t += 8) {
            float4 v0 = ntload4(src + 0 * LDQ);
            float4 v1 = ntload4(src + 1 * LDQ);
            float4 v2 = ntload4(src + 2 * LDQ);
            float4 v3 = ntload4(src + 3 * LDQ);
            float4 v4 = ntload4(src + 4 * LDQ);
            float4 v5 = ntload4(src + 5 * LDQ);
            float4 v6 = ntload4(src + 6 * LDQ);
            float4 v7 = ntload4(src + 7 * LDQ);
            src += 8 * LDQ;
            a0.x += v0.x; a0.y += v0.y; a0.z += v0.z; a0.w += v0.w;
            a1.x += v1.x; a1.y += v1.y; a1.z += v1.z; a1.w += v1.w;
            a2.x += v2.x; a2.y += v2.y; a2.z += v2.z; a2.w += v2.w;
            a3.x += v3.x; a3.y += v3.y; a3.z += v3.z; a3.w += v3.w;
            a4.x += v4.x; a4.y += v4.y; a4.z += v4.z; a4.w += v4.w;
            a5.x += v5.x; a5.y += v5.y; a5.z += v5.z; a5.w += v5.w;
            a6.x += v6.x; a6.y += v6.y; a6.z += v6.z; a6.w += v6.w;
            a7.x += v7.x; a7.y += v7.y; a7.z += v7.z; a7.w += v7.w;
        }
        float4 s;
        s.x = ((a0.x + a1.x) + (a2.x + a3.x)) + ((a4.x + a5.x) + (a6.x + a7.x));
        s.y = ((a0.y + a1.y) + (a2.y + a3.y)) + ((a4.y + a5.y) + (a6.y + a7.y));
        s.z = ((a0.z + a1.z) + (a2.z + a3.z)) + ((a4.z + a5.z) + (a6.z + a7.z));
        s.w = ((a0.w + a1.w) + (a2.w + a3.w)) + ((a4.w + a5.w) + (a6.w + a7.w));
        ((float4*)partial)[((size_t)mb * TC + tc) * (D_ / 4) + tid] = s;
        return;
    }

    if (blk < NPOOL + NW1T) {
        // W1 [m][k][e] f32  ->  w1t [m][e][k] bf16 ; 64x64 tiles via LDS transpose
        int bid = blk - NPOOL;                 // 0..191
        for (int i = 0; i < 4; ++i) {
            int tile = bid * 4 + i;            // 0..767
            int et = tile & 15;
            int kt = (tile >> 4) & 15;
            int mm = tile >> 8;
            int k0 = kt * 64, ee0 = et * 64;
#pragma unroll
            for (int sv = 0; sv < 4; ++sv) {
                int idx = sv * 256 + tid;
                int row = idx >> 4;
                int c4  = idx & 15;
                float4 v = ntload4((const float4*)(W1 + (size_t)mm * D_ * D_ + (size_t)(k0 + row) * D_ + ee0 + c4 * 4));
                *(float4*)&ldsf[row][c4 * 4] = v;
            }
            __syncthreads();
            int er = tid >> 2;
            int ks = (tid & 3) * 16;
            short8v v0, v1;
#pragma unroll
            for (int j = 0; j < 8; ++j) v0[j] = (short)f2bf(ldsf[ks + j][er]);
#pragma unroll
            for (int j = 0; j < 8; ++j) v1[j] = (short)f2bf(ldsf[ks + 8 + j][er]);
            size_t ob = ((size_t)mm * D_ + ee0 + er) * D_ + k0 + ks;
            *(short8v*)(w1t + ob)     = v0;
            *(short8v*)(w1t + ob + 8) = v1;
            __syncthreads();
        }
        return;
    }

    // W2 cast: w2p[m][k2][p] = bf16(W2[m][2k2][p]) | bf16(W2[m][2k2+1][p])<<16
    {
        int bid = blk - NPOOL - NW1T;          // 0..63
        const int TOT = M_ * (D_ / 2) * P_;    // 393216
        for (int i = bid * 256 + tid; i < TOT; i += NW2 * 256) {
            int p  = i & (P_ - 1);
            int k2 = (i >> 8) & (D_ / 2 - 1);
            int m  = i >> 17;
            size_t base = (size_t)m * D_ * P_ + (size_t)(2 * k2) * P_ + p;
            float f0 = __builtin_nontemporal_load(W2 + base);
            float f1 = __builtin_nontemporal_load(W2 + base + P_);
            w2p[i] = f2bf(f0) | (f2bf(f1) << 16);
        }
    }
}

// ---------------- Kernel 2: h = gelu(mean(partial) @ W1 + b1), bf16 MFMA ----------------
// grid (D/64=16, B/32=4, M) = 192 blocks, 256 threads = 4 waves.
// Tile 32(rows) x 64(cols), BK=64. LDS XOR-swizzled (16B chunk ^= row&7).
__global__ __launch_bounds__(256) void gemm1_mfma(const float* __restrict__ partial,
                                                  const short* __restrict__ w1t,
                                                  const float* __restrict__ b1,
                                                  float* __restrict__ h) {
    __shared__ __align__(16) short As[32 * 64];   // [row][k] bf16, 128B rows
    __shared__ __align__(16) short Bs[64 * 64];   // [col][k] bf16, 128B rows
    int m  = blockIdx.z;
    int b0 = blockIdx.y * 32;
    int e0 = blockIdx.x * 64;
    int tid = threadIdx.x;
    int l   = tid & 63;
    int w   = tid >> 6;
    int wr  = w & 1, wc = w >> 1;

    int arow = tid >> 3;          // 0..31 A row
    int k8   = tid & 7;           // 16B chunk (8 bf16)
    int bcol = tid >> 2;          // 0..63 B "row" (= W1 col)
    int bj   = tid & 3;           // 32B segment (2 chunks)

    const float* Abase = partial + ((size_t)(m * B_ + b0 + arow) * TC) * D_ + k8 * 8;
    const short* Bbase = w1t + ((size_t)m * D_ + e0 + bcol) * D_ + bj * 16;

    char* AsB = (char*)As;
    char* BsB = (char*)Bs;
    short8v* AsW  = (short8v*)(AsB + arow * 128 + ((k8 ^ (arow & 7)) << 4));
    short8v* BsW0 = (short8v*)(BsB + bcol * 128 + (((2 * bj)     ^ (bcol & 7)) << 4));
    short8v* BsW1 = (short8v*)(BsB + bcol * 128 + (((2 * bj + 1) ^ (bcol & 7)) << 4));

    f32x4 acc0 = {0.f, 0.f, 0.f, 0.f};
    f32x4 acc1 = {0.f, 0.f, 0.f, 0.f};
    const float inv = 1.0f / (float)T_;

    int ar  = wr * 16 + (l & 15);
    int bc0 = wc * 32 + (l & 15);
    int bc1 = bc0 + 16;
    int lh  = l >> 4;             // 0..3

    for (int it = 0; it < 16; ++it) {
        int k0 = it * 64;
        float4 p00 = *(const float4*)(Abase + k0);
        float4 p01 = *(const float4*)(Abase + k0 + 4);
        float4 p10 = *(const float4*)(Abase + D_ + k0);
        float4 p11 = *(const float4*)(Abase + D_ + k0 + 4);
        float4 p20 = *(const float4*)(Abase + 2 * D_ + k0);
        float4 p21 = *(const float4*)(Abase + 2 * D_ + k0 + 4);
        float4 p30 = *(const float4*)(Abase + 3 * D_ + k0);
        float4 p31 = *(const float4*)(Abase + 3 * D_ + k0 + 4);
        short8v bv0 = *(const short8v*)(Bbase + k0);
        short8v bv1 = *(const short8v*)(Bbase + k0 + 8);
        __syncthreads();   // previous iteration's frag reads done
        short8v av;
        av[0] = (short)f2bf(((p00.x + p10.x) + (p20.x + p30.x)) * inv);
        av[1] = (short)f2bf(((p00.y + p10.y) + (p20.y + p30.y)) * inv);
        av[2] = (short)f2bf(((p00.z + p10.z) + (p20.z + p30.z)) * inv);
        av[3] = (short)f2bf(((p00.w + p10.w) + (p20.w + p30.w)) * inv);
        av[4] = (short)f2bf(((p01.x + p11.x) + (p21.x + p31.x)) * inv);
        av[5] = (short)f2bf(((p01.y + p11.y) + (p21.y + p31.y)) * inv);
        av[6] = (short)f2bf(((p01.z + p11.z) + (p21.z + p31.z)) * inv);
        av[7] = (short)f2bf(((p01.w + p11.w) + (p21.w + p31.w)) * inv);
        *AsW  = av;
        *BsW0 = bv0;
        *BsW1 = bv1;
        __syncthreads();
#pragma unroll
        for (int kk = 0; kk < 2; ++kk) {
            int ch = kk * 4 + lh;
            short8v af  = *(const short8v*)(AsB + ar  * 128 + ((ch ^ (ar  & 7)) << 4));
            short8v bf0 = *(const short8v*)(BsB + bc0 * 128 + ((ch ^ (bc0 & 7)) << 4));
            short8v bf1 = *(const short8v*)(BsB + bc1 * 128 + ((ch ^ (bc1 & 7)) << 4));
            acc0 = __builtin_amdgcn_mfma_f32_16x16x32_bf16(af, bf0, acc0, 0, 0, 0);
            acc1 = __builtin_amdgcn_mfma_f32_16x16x32_bf16(af, bf1, acc1, 0, 0, 0);
        }
    }

    // epilogue: C/D layout col=lane&15, row=(lane>>4)*4+reg  [m89-verified]
    int colBase = e0 + wc * 32 + (l & 15);
    int rowBase = b0 + wr * 16 + lh * 4;
    const float is2 = 0.70710678118654752f;
#pragma unroll
    for (int n = 0; n < 2; ++n) {
        f32x4 acc = n ? acc1 : acc0;
        int col = colBase + n * 16;
        float bb = b1[m * D_ + col];
#pragma unroll
        for (int r = 0; r < 4; ++r) {
            float x = acc[r] + bb;
            float gx = 0.5f * x * (1.0f + erff(x * is2));
            h[(size_t)(m * B_ + rowBase + r) * D_ + col] = gx;
        }
    }
}

// ---------------- Kernel 3: z = h @ W2 + b2, LN, L2-normalize; split-K x2, 512 thr ----------------
__global__ __launch_bounds__(512) void gemm2_ln(const float* __restrict__ h,
                                                const unsigned int* __restrict__ w2p,
                                                const float* __restrict__ b2,
                                                const float* __restrict__ gamma,
                                                const float* __restrict__ beta,
                                                float* __restrict__ out) {
    int m  = blockIdx.y;
    int b0 = blockIdx.x * 2;
    int tid  = threadIdx.x;
    int p    = tid & 255;
    int half = tid >> 8;
    int lane = tid & 63;
    int w    = (tid >> 6) & 3;

    __shared__ float accs[2][2][256];   // [half][row][p]
    __shared__ float redA[2][4];
    __shared__ float redB[2][4];
    __shared__ float redC[2][4];

    const unsigned int* Wp = w2p + (size_t)m * (D_ / 2) * P_ + (size_t)half * 256 * P_ + p;
    const float* hb = h + ((size_t)m * B_ + b0) * D_ + half * 512;

    float acc0 = 0.f, acc1 = 0.f;
#pragma unroll 8
    for (int q = 0; q < 128; ++q) {
        unsigned int u0 = Wp[(size_t)(2 * q) * P_];
        unsigned int u1 = Wp[(size_t)(2 * q + 1) * P_];
        float w0 = __uint_as_float(u0 << 16);
        float w1 = __uint_as_float(u0 & 0xffff0000u);
        float w2 = __uint_as_float(u1 << 16);
        float w3 = __uint_as_float(u1 & 0xffff0000u);
        float4 h0 = *(const float4*)(hb + 4 * q);          // uniform
        float4 h1 = *(const float4*)(hb + D_ + 4 * q);     // uniform
        acc0 += h0.x * w0 + h0.y * w1 + h0.z * w2 + h0.w * w3;
        acc1 += h1.x * w0 + h1.y * w1 + h1.z * w2 + h1.w * w3;
    }
    accs[half][0][p] = acc0;
    accs[half][1][p] = acc1;
    __syncthreads();

    int g = half;
    float z = accs[0][g][p] + accs[1][g][p] + b2[m * P_ + p];

    float s1 = z, s2 = z * z;
    for (int off = 32; off > 0; off >>= 1) {
        s1 += __shfl_xor(s1, off);
        s2 += __shfl_xor(s2, off);
    }
    if (lane == 0) { redA[g][w] = s1; redB[g][w] = s2; }
    __syncthreads();
    s1 = (redA[g][0] + redA[g][1]) + (redA[g][2] + redA[g][3]);
    s2 = (redB[g][0] + redB[g][1]) + (redB[g][2] + redB[g][3]);
    float mu  = s1 * (1.0f / P_);
    float var = s2 * (1.0f / P_) - mu * mu;
    float inv = 1.0f / sqrtf(var + 1e-5f);
    z = (z - mu) * inv * gamma[m * P_ + p] + beta[m * P_ + p];

    float s = z * z;
    for (int off = 32; off > 0; off >>= 1) s += __shfl_xor(s, off);
    if (lane == 0) redC[g][w] = s;
    __syncthreads();
    s = (redC[g][0] + redC[g][1]) + (redC[g][2] + redC[g][3]);
    float n = sqrtf(s);
    out[((size_t)m * B_ + b0 + g) * P_ + p] = z / fmaxf(n, 1e-12f);
}

extern "C" void kernel_launch(void* const* d_in, const int* in_sizes, int n_in,
                              void* d_out, int out_size, void* d_ws, size_t ws_size,
                              hipStream_t stream) {
    const float* feats = (const float*)d_in[0];
    const float* W1    = (const float*)d_in[1];
    const float* b1    = (const float*)d_in[2];
    const float* W2    = (const float*)d_in[3];
    const float* b2    = (const float*)d_in[4];
    const float* gamma = (const float*)d_in[5];
    const float* beta  = (const float*)d_in[6];
    float* out = (float*)d_out;

    float* wsf = (float*)d_ws;
    const size_t NPART = (size_t)M_ * B_ * TC * D_;              // 1,572,864 floats (6 MB)
    float*        partial = wsf;
    unsigned int* w2p     = (unsigned int*)(wsf + NPART);        // 393216 u32 (1.5 MB)
    float*        hbuf    = wsf + NPART + 393216;                // 393216 f32 (1.5 MB)
    short*        w1t     = (short*)(wsf + NPART + 2 * 393216);  // M*D*D bf16 (6 MB)
    // total ws: 15 MB

    pool_and_cast<<<NPOOL + NW1T + NW2, 256, 0, stream>>>(feats, W1, W2, partial, w1t, w2p);
    dim3 g2(D_ / 64, B_ / 32, M_);
    gemm1_mfma<<<g2, 256, 0, stream>>>(partial, w1t, b1, hbuf);
    dim3 g3(B_ / 2, M_);
    gemm2_ln<<<g3, 512, 0, stream>>>(hbuf, w2p, b2, gamma, beta, out);
}